// Round 1
// baseline (1874.166 us; speedup 1.0000x reference)
//
#include <hip/hip_runtime.h>

#define N_NODES 150000
#define E_EDGES 1500000
#define C_CLUST 50000
#define P_PAIRS 300000
#define E2_EDGES 600000
#define B_BATCH 16
#define NCLS_ 10
#define EPS_ 1e-5f

static __device__ __forceinline__ void atomicMaxFloatPos(float* addr, float v) {
    // valid for non-negative floats (bit pattern monotone); init must be 0.0f
    atomicMax((int*)addr, __float_as_int(v));
}

__global__ void fill_kernel(float* __restrict__ p, float v, int n) {
    int i = blockIdx.x * blockDim.x + threadIdx.x;
    if (i < n) p[i] = v;
}

__global__ void bias_init_kernel(float* __restrict__ out, const float* __restrict__ bias, int total) {
    int i = blockIdx.x * blockDim.x + threadIdx.x;
    if (i < total) out[i] = bias[i & 63];
}

__global__ void deg_kernel(const int* __restrict__ col, const float* __restrict__ ew,
                           float* __restrict__ deg, int E) {
    int e = blockIdx.x * blockDim.x + threadIdx.x;
    if (e < E) atomicAdd(&deg[col[e]], ew[e]);
}

__global__ void dis_kernel(float* __restrict__ deg, int n) {
    int i = blockIdx.x * blockDim.x + threadIdx.x;
    if (i < n) deg[i] = rsqrtf(deg[i] + 1.0f);  // +1 = self-loop weight, always > 0
}

// out[col] += dis[row]*ew*dis[col] * h[row]; edges e<E from arrays, e>=E are self loops
__global__ void gcn_scatter_kernel(const float* __restrict__ h, const int* __restrict__ ei,
                                   const float* __restrict__ ew, const float* __restrict__ dis,
                                   float* __restrict__ out, int E, int n) {
    int t = blockIdx.x * blockDim.x + threadIdx.x;
    int g = t >> 6, lane = t & 63;
    if (g >= E + n) return;
    int r, c; float w;
    if (g < E) { r = ei[g]; c = ei[E + g]; w = ew[g]; }
    else       { r = g - E; c = r; w = 1.0f; }
    float norm = dis[r] * w * dis[c];
    atomicAdd(&out[c * 64 + lane], norm * h[r * 64 + lane]);
}

// Y[n x 64] = (relu_in? relu(X) : X) @ W[K x 64] (+bias) (relu_out?)
// X row = [X1 row (64) | X2 row (64)] when HAS_X2 (K=128)
template<int K, bool RELU_IN, bool RELU_OUT, bool HAS_X2, bool HAS_BIAS>
__global__ __launch_bounds__(256) void gemm_kernel(const float* __restrict__ X1,
                                                   const float* __restrict__ X2,
                                                   const float* __restrict__ W,
                                                   const float* __restrict__ bias,
                                                   float* __restrict__ Y, int n) {
    constexpr int KP = K + 4;  // pad to break LDS bank aliasing on row-broadcast reads
    __shared__ float Xs[64 * KP];
    __shared__ float Ws[K * 64];
    const int tid = threadIdx.x;
    const int r0 = blockIdx.x * 64;

    for (int i = tid; i < K * 16; i += 256)       // K*64 floats as float4
        ((float4*)Ws)[i] = ((const float4*)W)[i];

    for (int i = tid; i < 16 * K; i += 256) {     // 64 rows * K floats / 4
        int row = i / (K / 4);
        int k4  = (i % (K / 4)) * 4;
        int r = r0 + row;
        float4 v = make_float4(0.f, 0.f, 0.f, 0.f);
        if (r < n) {
            const float* src = (HAS_X2 && k4 >= 64) ? (X2 + (size_t)r * 64 + (k4 - 64))
                                                    : (X1 + (size_t)r * 64 + k4);
            v = *(const float4*)src;
            if (RELU_IN) {
                v.x = fmaxf(v.x, 0.f); v.y = fmaxf(v.y, 0.f);
                v.z = fmaxf(v.z, 0.f); v.w = fmaxf(v.w, 0.f);
            }
        }
        *(float4*)&Xs[row * KP + k4] = v;
    }
    __syncthreads();

    const int tx = tid & 15, ty = tid >> 4;
    const int c0 = tx * 4, rl = ty * 4;
    float acc[4][4] = {};

    for (int k = 0; k < K; k += 4) {
        float4 xv[4], wv[4];
        #pragma unroll
        for (int i = 0; i < 4; ++i) xv[i] = *(const float4*)&Xs[(rl + i) * KP + k];
        #pragma unroll
        for (int i = 0; i < 4; ++i) wv[i] = *(const float4*)&Ws[(k + i) * 64 + c0];
        #pragma unroll
        for (int i = 0; i < 4; ++i) {
            const float* xp = (const float*)&xv[i];
            #pragma unroll
            for (int kk = 0; kk < 4; ++kk) {
                const float* wp = (const float*)&wv[kk];
                #pragma unroll
                for (int j = 0; j < 4; ++j) acc[i][j] += xp[kk] * wp[j];
            }
        }
    }

    #pragma unroll
    for (int i = 0; i < 4; ++i) {
        int r = r0 + rl + i;
        if (r < n) {
            float o[4];
            #pragma unroll
            for (int j = 0; j < 4; ++j) {
                o[j] = acc[i][j];
                if (HAS_BIAS) o[j] += bias[c0 + j];
                if (RELU_OUT) o[j] = fmaxf(o[j], 0.f);
            }
            *(float4*)&Y[(size_t)r * 64 + c0] = make_float4(o[0], o[1], o[2], o[3]);
        }
    }
}

// sorted-segment sum+max pooling into xs[B][256] at [col_off .. col_off+64) sum, [+64..+128) max
__global__ void batch_pool_kernel(const float* __restrict__ X, const int* __restrict__ batch,
                                  int n, float* __restrict__ xs, int col_off, int rows_per_block) {
    int lane = threadIdx.x;  // 64 threads
    int rstart = blockIdx.x * rows_per_block;
    if (rstart >= n) return;
    int rend = min(rstart + rows_per_block, n);
    float s = 0.f, m = 0.f;
    int cur = batch[rstart];
    for (int r = rstart; r < rend; ++r) {
        int b = batch[r];
        if (b != cur) {
            atomicAdd(&xs[cur * 256 + col_off + lane], s);
            atomicMaxFloatPos(&xs[cur * 256 + col_off + 64 + lane], m);
            s = 0.f; m = 0.f; cur = b;
        }
        float v = X[(size_t)r * 64 + lane];
        s += v; m = fmaxf(m, v);
    }
    atomicAdd(&xs[cur * 256 + col_off + lane], s);
    atomicMaxFloatPos(&xs[cur * 256 + col_off + 64 + lane], m);
}

__global__ void cover_pool_kernel(const float* __restrict__ X, const int* __restrict__ cn,
                                  const int* __restrict__ cc, float* __restrict__ xp_sum,
                                  float* __restrict__ xp_max, int P) {
    int t = blockIdx.x * blockDim.x + threadIdx.x;
    int p = t >> 6, lane = t & 63;
    if (p >= P) return;
    int nsrc = cn[p], c = cc[p];
    float v = X[(size_t)nsrc * 64 + lane];
    atomicAdd(&xp_sum[(size_t)c * 64 + lane], v);
    atomicMaxFloatPos(&xp_max[(size_t)c * 64 + lane], v);
}

// BN (over batch dim) -> lin1+relu -> lin2 -> softmax, single block
__global__ __launch_bounds__(256) void head_kernel(const float* __restrict__ xs,
    const float* __restrict__ gamma, const float* __restrict__ beta,
    const float* __restrict__ W1, const float* __restrict__ b1,
    const float* __restrict__ W2, const float* __restrict__ b2,
    float* __restrict__ out) {
    __shared__ float hn[16][256];
    __shared__ float h2[16][64];
    __shared__ float logits[16][10];
    int t = threadIdx.x;

    float v[16];
    float mu = 0.f;
    #pragma unroll
    for (int b = 0; b < 16; ++b) { v[b] = xs[b * 256 + t]; mu += v[b]; }
    mu *= (1.f / 16.f);
    float var = 0.f;
    #pragma unroll
    for (int b = 0; b < 16; ++b) { float d = v[b] - mu; var += d * d; }
    var *= (1.f / 16.f);
    float sc = rsqrtf(var + EPS_) * gamma[t];
    float bt = beta[t];
    #pragma unroll
    for (int b = 0; b < 16; ++b) hn[b][t] = (v[b] - mu) * sc + bt;
    __syncthreads();

    {
        int c = t & 63, bg = t >> 6;
        for (int j = 0; j < 4; ++j) {
            int b = bg * 4 + j;
            float acc = b1[c];
            for (int k = 0; k < 256; ++k) acc += hn[b][k] * W1[k * 64 + c];
            h2[b][c] = fmaxf(acc, 0.f);
        }
    }
    __syncthreads();

    if (t < 160) {
        int b = t / 10, c = t % 10;
        float acc = b2[c];
        for (int k = 0; k < 64; ++k) acc += h2[b][k] * W2[k * 10 + c];
        logits[b][c] = acc;
    }
    __syncthreads();

    if (t < 16) {
        float m = -1e30f;
        for (int c = 0; c < 10; ++c) m = fmaxf(m, logits[t][c]);
        float s = 0.f;
        float e[10];
        for (int c = 0; c < 10; ++c) { e[c] = expf(logits[t][c] - m); s += e[c]; }
        float inv = 1.f / s;
        for (int c = 0; c < 10; ++c) out[t * 10 + c] = e[c] * inv;
    }
}

extern "C" void kernel_launch(void* const* d_in, const int* in_sizes, int n_in,
                              void* d_out, int out_size, void* d_ws, size_t ws_size,
                              hipStream_t stream) {
    (void)in_sizes; (void)n_in; (void)out_size; (void)ws_size;
    const float* x      = (const float*)d_in[0];
    const int*   ei1    = (const int*)d_in[1];
    const float* w1     = (const float*)d_in[2];
    const int*   batch  = (const int*)d_in[3];
    const int*   covern = (const int*)d_in[4];
    const int*   coverc = (const int*)d_in[5];
    const int*   ei2    = (const int*)d_in[6];
    const float* w2     = (const float*)d_in[7];
    const int*   batch2 = (const int*)d_in[8];
    const float* W_in0  = (const float*)d_in[9];
    const float* b_in0  = (const float*)d_in[10];
    const float* W_in1  = (const float*)d_in[11];
    const float* b_in1  = (const float*)d_in[12];
    const float* Wl_in  = (const float*)d_in[13];
    const float* bl_in  = (const float*)d_in[14];
    const float* W_b0   = (const float*)d_in[15];
    const float* b_b0   = (const float*)d_in[16];
    const float* W_b1   = (const float*)d_in[17];
    const float* b_b1   = (const float*)d_in[18];
    const float* Wl_b   = (const float*)d_in[19];
    const float* bl_b   = (const float*)d_in[20];
    const float* gamma  = (const float*)d_in[21];
    const float* beta   = (const float*)d_in[22];
    const float* lin1W  = (const float*)d_in[23];
    const float* lin1b  = (const float*)d_in[24];
    const float* lin2W  = (const float*)d_in[25];
    const float* lin2b  = (const float*)d_in[26];
    float* out = (float*)d_out;

    char* ws = (char*)d_ws;
    size_t off = 0;
    auto alloc = [&](size_t bytes) {
        char* p = ws + off; off += (bytes + 255) & ~(size_t)255; return (float*)p;
    };
    float* A  = alloc((size_t)N_NODES * 64 * 4);
    float* Bb = alloc((size_t)N_NODES * 64 * 4);
    float* Cc = alloc((size_t)N_NODES * 64 * 4);
    float* D  = alloc((size_t)N_NODES * 4);
    float* XS = alloc((size_t)B_BATCH * 256 * 4);
    float* A2     = A  + (size_t)C_CLUST * 64;   // aggb2 (A is free by then)
    float* xp_sum = Bb;                          // Bb free after x1_top gemm
    float* xp_max = Bb + (size_t)C_CLUST * 64;

    auto cdiv = [](long long a, long long b) { return (int)((a + b - 1) / b); };

    // ---- init ----
    fill_kernel<<<cdiv(B_BATCH * 256, 256), 256, 0, stream>>>(XS, 0.f, B_BATCH * 256);

    // ---- graph 1 normalization ----
    fill_kernel<<<cdiv(N_NODES, 256), 256, 0, stream>>>(D, 0.f, N_NODES);
    deg_kernel<<<cdiv(E_EDGES, 256), 256, 0, stream>>>(ei1 + E_EDGES, w1, D, E_EDGES);
    dis_kernel<<<cdiv(N_NODES, 256), 256, 0, stream>>>(D, N_NODES);

    // ---- block 1 ----
    // h1 = x @ W_in0 -> A
    gemm_kernel<64, false, false, false, false><<<cdiv(N_NODES, 64), 256, 0, stream>>>(
        x, nullptr, W_in0, nullptr, A, N_NODES);
    // agg1 = b_in0 + scatter(h1) -> Bb
    bias_init_kernel<<<cdiv((long long)N_NODES * 64, 256), 256, 0, stream>>>(Bb, b_in0, N_NODES * 64);
    gcn_scatter_kernel<<<cdiv((long long)(E_EDGES + N_NODES) * 64, 256), 256, 0, stream>>>(
        A, ei1, w1, D, Bb, E_EDGES, N_NODES);
    // h2 = relu(agg1) @ W_in1 -> A
    gemm_kernel<64, true, false, false, false><<<cdiv(N_NODES, 64), 256, 0, stream>>>(
        Bb, nullptr, W_in1, nullptr, A, N_NODES);
    // agg2 = b_in1 + scatter(h2) -> Cc
    bias_init_kernel<<<cdiv((long long)N_NODES * 64, 256), 256, 0, stream>>>(Cc, b_in1, N_NODES * 64);
    gcn_scatter_kernel<<<cdiv((long long)(E_EDGES + N_NODES) * 64, 256), 256, 0, stream>>>(
        A, ei1, w1, D, Cc, E_EDGES, N_NODES);
    // x1_top = relu([relu(agg1)|relu(agg2)] @ Wl_in + bl_in) -> A
    gemm_kernel<128, true, true, true, true><<<cdiv(N_NODES, 64), 256, 0, stream>>>(
        Bb, Cc, Wl_in, bl_in, A, N_NODES);

    // ---- pooling ----
    batch_pool_kernel<<<cdiv(N_NODES, 512), 64, 0, stream>>>(A, batch, N_NODES, XS, 0, 512);
    fill_kernel<<<cdiv((long long)2 * C_CLUST * 64, 256), 256, 0, stream>>>(xp_sum, 0.f, 2 * C_CLUST * 64);
    cover_pool_kernel<<<cdiv((long long)P_PAIRS * 64, 256), 256, 0, stream>>>(
        A, covern, coverc, xp_sum, xp_max, P_PAIRS);

    // ---- graph 2 normalization ----
    fill_kernel<<<cdiv(C_CLUST, 256), 256, 0, stream>>>(D, 0.f, C_CLUST);
    deg_kernel<<<cdiv(E2_EDGES, 256), 256, 0, stream>>>(ei2 + E2_EDGES, w2, D, E2_EDGES);
    dis_kernel<<<cdiv(C_CLUST, 256), 256, 0, stream>>>(D, C_CLUST);

    // ---- block 2 ----
    // hb = [xp_sum|xp_max] @ W_b0 -> Cc
    gemm_kernel<128, false, false, true, false><<<cdiv(C_CLUST, 64), 256, 0, stream>>>(
        xp_sum, xp_max, W_b0, nullptr, Cc, C_CLUST);
    // aggb1 = b_b0 + scatter(hb) -> A
    bias_init_kernel<<<cdiv((long long)C_CLUST * 64, 256), 256, 0, stream>>>(A, b_b0, C_CLUST * 64);
    gcn_scatter_kernel<<<cdiv((long long)(E2_EDGES + C_CLUST) * 64, 256), 256, 0, stream>>>(
        Cc, ei2, w2, D, A, E2_EDGES, C_CLUST);
    // hb2 = relu(aggb1) @ W_b1 -> Cc
    gemm_kernel<64, true, false, false, false><<<cdiv(C_CLUST, 64), 256, 0, stream>>>(
        A, nullptr, W_b1, nullptr, Cc, C_CLUST);
    // aggb2 = b_b1 + scatter(hb2) -> A2
    bias_init_kernel<<<cdiv((long long)C_CLUST * 64, 256), 256, 0, stream>>>(A2, b_b1, C_CLUST * 64);
    gcn_scatter_kernel<<<cdiv((long long)(E2_EDGES + C_CLUST) * 64, 256), 256, 0, stream>>>(
        Cc, ei2, w2, D, A2, E2_EDGES, C_CLUST);
    // x2_top = relu([relu(aggb1)|relu(aggb2)] @ Wl_b + bl_b) -> Cc
    gemm_kernel<128, true, true, true, true><<<cdiv(C_CLUST, 64), 256, 0, stream>>>(
        A, A2, Wl_b, bl_b, Cc, C_CLUST);

    // ---- pooling 2 ----
    batch_pool_kernel<<<cdiv(C_CLUST, 512), 64, 0, stream>>>(Cc, batch2, C_CLUST, XS, 128, 512);

    // ---- head ----
    head_kernel<<<1, 256, 0, stream>>>(XS, gamma, beta, lin1W, lin1b, lin2W, lin2b, out);
}

// Round 4
// 1014.339 us; speedup vs baseline: 1.8477x; 1.8477x over previous
//
#include <hip/hip_runtime.h>

#define N_NODES 150000
#define E_EDGES 1500000
#define C_CLUST 50000
#define P_PAIRS 300000
#define E2_EDGES 600000
#define B_BATCH 16
#define EPS_ 1e-5f

static __device__ __forceinline__ void atomicMaxFloatPos(float* addr, float v) {
    // valid for non-negative floats (bit pattern monotone); init must be 0.0f
    atomicMax((int*)addr, __float_as_int(v));
}

// ---------------- degree + histogram ----------------

__global__ void deg_cnt_kernel(const int* __restrict__ col, const float* __restrict__ ew,
                               float* __restrict__ deg, int* __restrict__ cnt, int E) {
    int e = blockIdx.x * blockDim.x + threadIdx.x;
    if (e < E) {
        int c = col[e];
        atomicAdd(&deg[c], ew[e]);
        atomicAdd(&cnt[c], 1);
    }
}

__global__ void dis_kernel(float* __restrict__ deg, int n) {
    int i = blockIdx.x * blockDim.x + threadIdx.x;
    if (i < n) deg[i] = rsqrtf(deg[i] + 1.0f);  // +1 = self-loop weight, always > 0
}

__global__ void cnt_ids_kernel(const int* __restrict__ ids, int* __restrict__ cnt, int P) {
    int p = blockIdx.x * blockDim.x + threadIdx.x;
    if (p < P) atomicAdd(&cnt[ids[p]], 1);
}

// ---------------- exclusive scan (3 kernels) ----------------
__global__ __launch_bounds__(256) void scan1_kernel(const int* __restrict__ cnt,
                                                    int* __restrict__ exc,
                                                    int* __restrict__ bsum, int n) {
    __shared__ int sh[256];
    int t = threadIdx.x;
    int base = blockIdx.x * 1024 + t * 4;
    int v[4];
    #pragma unroll
    for (int i = 0; i < 4; ++i) { int idx = base + i; v[i] = (idx < n) ? cnt[idx] : 0; }
    int tsum = v[0] + v[1] + v[2] + v[3];
    sh[t] = tsum; __syncthreads();
    for (int o = 1; o < 256; o <<= 1) {
        int add = (t >= o) ? sh[t - o] : 0;
        __syncthreads();
        sh[t] += add;
        __syncthreads();
    }
    int run = sh[t] - tsum;  // exclusive prefix for this thread
    #pragma unroll
    for (int i = 0; i < 4; ++i) { int idx = base + i; if (idx < n) exc[idx] = run; run += v[i]; }
    if (t == 255) bsum[blockIdx.x] = sh[255];
}

__global__ __launch_bounds__(256) void scan2_kernel(int* __restrict__ bsum, int nb,
                                                    int* __restrict__ total_out) {
    __shared__ int sh[256];
    int t = threadIdx.x;
    int val = (t < nb) ? bsum[t] : 0;
    sh[t] = val; __syncthreads();
    for (int o = 1; o < 256; o <<= 1) {
        int add = (t >= o) ? sh[t - o] : 0;
        __syncthreads();
        sh[t] += add;
        __syncthreads();
    }
    if (t < nb) bsum[t] = sh[t] - val;            // exclusive
    if (t == nb - 1) *total_out = sh[t];          // grand total -> rowptr[n]
}

__global__ void scan3_kernel(const int* __restrict__ exc, const int* __restrict__ bsum,
                             int* __restrict__ rowptr, int* __restrict__ next, int n) {
    int i = blockIdx.x * blockDim.x + threadIdx.x;
    if (i < n) {
        int v = exc[i] + bsum[i >> 10];
        rowptr[i] = v;
        next[i] = v;
    }
}

// ---------------- bucketing ----------------

__global__ void bucket_kernel(const int* __restrict__ ei, const float* __restrict__ ew,
                              const float* __restrict__ dis, int* __restrict__ next,
                              int* __restrict__ src, float* __restrict__ nw, int E) {
    int e = blockIdx.x * blockDim.x + threadIdx.x;
    if (e >= E) return;
    int r = ei[e], c = ei[E + e];
    int pos = atomicAdd(&next[c], 1);
    src[pos] = r;
    nw[pos] = dis[r] * ew[e] * dis[c];
}

__global__ void bucketP_kernel(const int* __restrict__ cn, const int* __restrict__ cc,
                               int* __restrict__ next, int* __restrict__ srcn, int P) {
    int p = blockIdx.x * blockDim.x + threadIdx.x;
    if (p >= P) return;
    int pos = atomicAdd(&next[cc[p]], 1);
    srcn[pos] = cn[p];
}

// ---------------- GCN gather: out[c] = bias + dis[c]^2*h[c] + sum nw[j]*h[src[j]] ----------------

__global__ void gcn_gather_kernel(const float* __restrict__ h, const int* __restrict__ rowptr,
                                  const int* __restrict__ src, const float* __restrict__ nw,
                                  const float* __restrict__ dis, const float* __restrict__ bias,
                                  float* __restrict__ out, int n) {
    int t = blockIdx.x * blockDim.x + threadIdx.x;
    int c = t >> 6, lane = t & 63;
    if (c >= n) return;
    float d = dis[c];
    float acc = bias[lane] + d * d * h[(size_t)c * 64 + lane];
    int j = rowptr[c], e1 = rowptr[c + 1];
    for (; j + 3 < e1; j += 4) {
        int   r0 = src[j],  r1 = src[j + 1], r2 = src[j + 2], r3 = src[j + 3];
        float w0 = nw[j],   w1 = nw[j + 1],  w2 = nw[j + 2],  w3 = nw[j + 3];
        float h0 = h[(size_t)r0 * 64 + lane];
        float h1 = h[(size_t)r1 * 64 + lane];
        float h2 = h[(size_t)r2 * 64 + lane];
        float h3 = h[(size_t)r3 * 64 + lane];
        acc += w0 * h0; acc += w1 * h1; acc += w2 * h2; acc += w3 * h3;
    }
    for (; j < e1; ++j) acc += nw[j] * h[(size_t)src[j] * 64 + lane];
    out[(size_t)c * 64 + lane] = acc;
}

// cover gather: sum + max per cluster, no atomics, no init needed
__global__ void cover_gather_kernel(const float* __restrict__ X, const int* __restrict__ rowptr,
                                    const int* __restrict__ srcn, float* __restrict__ xp_sum,
                                    float* __restrict__ xp_max, int C) {
    int t = blockIdx.x * blockDim.x + threadIdx.x;
    int c = t >> 6, lane = t & 63;
    if (c >= C) return;
    float s = 0.f, m = 0.f;
    int j = rowptr[c], e1 = rowptr[c + 1];
    for (; j + 1 < e1; j += 2) {
        float v0 = X[(size_t)srcn[j] * 64 + lane];
        float v1 = X[(size_t)srcn[j + 1] * 64 + lane];
        s += v0 + v1; m = fmaxf(m, fmaxf(v0, v1));
    }
    if (j < e1) {
        float v = X[(size_t)srcn[j] * 64 + lane];
        s += v; m = fmaxf(m, v);
    }
    xp_sum[(size_t)c * 64 + lane] = s;
    xp_max[(size_t)c * 64 + lane] = m;
}

// ---------------- GEMM: Y[n x 64] = (relu_in? relu(X) : X) @ W[K x 64] (+bias)(relu_out?) ----------------

template<int K, bool RELU_IN, bool RELU_OUT, bool HAS_X2, bool HAS_BIAS>
__global__ __launch_bounds__(256) void gemm_kernel(const float* __restrict__ X1,
                                                   const float* __restrict__ X2,
                                                   const float* __restrict__ W,
                                                   const float* __restrict__ bias,
                                                   float* __restrict__ Y, int n) {
    constexpr int KP = K + 4;
    __shared__ float Xs[64 * KP];
    __shared__ float Ws[K * 64];
    const int tid = threadIdx.x;
    const int r0 = blockIdx.x * 64;

    for (int i = tid; i < K * 16; i += 256)
        ((float4*)Ws)[i] = ((const float4*)W)[i];

    for (int i = tid; i < 16 * K; i += 256) {
        int row = i / (K / 4);
        int k4  = (i % (K / 4)) * 4;
        int r = r0 + row;
        float4 v = make_float4(0.f, 0.f, 0.f, 0.f);
        if (r < n) {
            const float* s = (HAS_X2 && k4 >= 64) ? (X2 + (size_t)r * 64 + (k4 - 64))
                                                  : (X1 + (size_t)r * 64 + k4);
            v = *(const float4*)s;
            if (RELU_IN) {
                v.x = fmaxf(v.x, 0.f); v.y = fmaxf(v.y, 0.f);
                v.z = fmaxf(v.z, 0.f); v.w = fmaxf(v.w, 0.f);
            }
        }
        *(float4*)&Xs[row * KP + k4] = v;
    }
    __syncthreads();

    const int tx = tid & 15, ty = tid >> 4;
    const int c0 = tx * 4, rl = ty * 4;
    float acc[4][4] = {};

    for (int k = 0; k < K; k += 4) {
        float4 xv[4], wv[4];
        #pragma unroll
        for (int i = 0; i < 4; ++i) xv[i] = *(const float4*)&Xs[(rl + i) * KP + k];
        #pragma unroll
        for (int i = 0; i < 4; ++i) wv[i] = *(const float4*)&Ws[(k + i) * 64 + c0];
        #pragma unroll
        for (int i = 0; i < 4; ++i) {
            const float* xp = (const float*)&xv[i];
            #pragma unroll
            for (int kk = 0; kk < 4; ++kk) {
                const float* wp = (const float*)&wv[kk];
                #pragma unroll
                for (int j = 0; j < 4; ++j) acc[i][j] += xp[kk] * wp[j];
            }
        }
    }

    #pragma unroll
    for (int i = 0; i < 4; ++i) {
        int r = r0 + rl + i;
        if (r < n) {
            float o[4];
            #pragma unroll
            for (int j = 0; j < 4; ++j) {
                o[j] = acc[i][j];
                if (HAS_BIAS) o[j] += bias[c0 + j];
                if (RELU_OUT) o[j] = fmaxf(o[j], 0.f);
            }
            *(float4*)&Y[(size_t)r * 64 + c0] = make_float4(o[0], o[1], o[2], o[3]);
        }
    }
}

// ---------------- sorted-segment batch pooling ----------------

__global__ void batch_pool_kernel(const float* __restrict__ X, const int* __restrict__ batch,
                                  int n, float* __restrict__ xs, int col_off, int rows_per_block) {
    int lane = threadIdx.x;  // 64 threads
    int rstart = blockIdx.x * rows_per_block;
    if (rstart >= n) return;
    int rend = min(rstart + rows_per_block, n);
    float s = 0.f, m = 0.f;
    int cur = batch[rstart];
    for (int r = rstart; r < rend; ++r) {
        int b = batch[r];
        if (b != cur) {
            atomicAdd(&xs[cur * 256 + col_off + lane], s);
            atomicMaxFloatPos(&xs[cur * 256 + col_off + 64 + lane], m);
            s = 0.f; m = 0.f; cur = b;
        }
        float v = X[(size_t)r * 64 + lane];
        s += v; m = fmaxf(m, v);
    }
    atomicAdd(&xs[cur * 256 + col_off + lane], s);
    atomicMaxFloatPos(&xs[cur * 256 + col_off + 64 + lane], m);
}

// ---------------- head: BN -> lin1+relu -> lin2 -> softmax ----------------

__global__ __launch_bounds__(256) void head_kernel(const float* __restrict__ xs,
    const float* __restrict__ gamma, const float* __restrict__ beta,
    const float* __restrict__ W1, const float* __restrict__ b1,
    const float* __restrict__ W2, const float* __restrict__ b2,
    float* __restrict__ out) {
    __shared__ float hn[16][256];
    __shared__ float h2[16][64];
    __shared__ float logits[16][10];
    int t = threadIdx.x;

    float v[16];
    float mu = 0.f;
    #pragma unroll
    for (int b = 0; b < 16; ++b) { v[b] = xs[b * 256 + t]; mu += v[b]; }
    mu *= (1.f / 16.f);
    float var = 0.f;
    #pragma unroll
    for (int b = 0; b < 16; ++b) { float d = v[b] - mu; var += d * d; }
    var *= (1.f / 16.f);
    float sc = rsqrtf(var + EPS_) * gamma[t];
    float bt = beta[t];
    #pragma unroll
    for (int b = 0; b < 16; ++b) hn[b][t] = (v[b] - mu) * sc + bt;
    __syncthreads();

    {
        int c = t & 63, bg = t >> 6;
        for (int j = 0; j < 4; ++j) {
            int b = bg * 4 + j;
            float acc = b1[c];
            for (int k = 0; k < 256; ++k) acc += hn[b][k] * W1[k * 64 + c];
            h2[b][c] = fmaxf(acc, 0.f);
        }
    }
    __syncthreads();

    if (t < 160) {
        int b = t / 10, c = t % 10;
        float acc = b2[c];
        for (int k = 0; k < 64; ++k) acc += h2[b][k] * W2[k * 10 + c];
        logits[b][c] = acc;
    }
    __syncthreads();

    if (t < 16) {
        float m = -1e30f;
        for (int c = 0; c < 10; ++c) m = fmaxf(m, logits[t][c]);
        float s = 0.f;
        float e[10];
        for (int c = 0; c < 10; ++c) { e[c] = expf(logits[t][c] - m); s += e[c]; }
        float inv = 1.f / s;
        for (int c = 0; c < 10; ++c) out[t * 10 + c] = e[c] * inv;
    }
}

extern "C" void kernel_launch(void* const* d_in, const int* in_sizes, int n_in,
                              void* d_out, int out_size, void* d_ws, size_t ws_size,
                              hipStream_t stream) {
    (void)in_sizes; (void)n_in; (void)out_size; (void)ws_size;
    const float* x      = (const float*)d_in[0];
    const int*   ei1    = (const int*)d_in[1];
    const float* w1     = (const float*)d_in[2];
    const int*   batch  = (const int*)d_in[3];
    const int*   covern = (const int*)d_in[4];
    const int*   coverc = (const int*)d_in[5];
    const int*   ei2    = (const int*)d_in[6];
    const float* w2     = (const float*)d_in[7];
    const int*   batch2 = (const int*)d_in[8];
    const float* W_in0  = (const float*)d_in[9];
    const float* b_in0  = (const float*)d_in[10];
    const float* W_in1  = (const float*)d_in[11];
    const float* b_in1  = (const float*)d_in[12];
    const float* Wl_in  = (const float*)d_in[13];
    const float* bl_in  = (const float*)d_in[14];
    const float* W_b0   = (const float*)d_in[15];
    const float* b_b0   = (const float*)d_in[16];
    const float* W_b1   = (const float*)d_in[17];
    const float* b_b1   = (const float*)d_in[18];
    const float* Wl_b   = (const float*)d_in[19];
    const float* bl_b   = (const float*)d_in[20];
    const float* gamma  = (const float*)d_in[21];
    const float* beta   = (const float*)d_in[22];
    const float* lin1W  = (const float*)d_in[23];
    const float* lin1b  = (const float*)d_in[24];
    const float* lin2W  = (const float*)d_in[25];
    const float* lin2b  = (const float*)d_in[26];
    float* out = (float*)d_out;

    char* ws = (char*)d_ws;
    size_t off = 0;
    auto alloc = [&](size_t bytes) {
        char* p = ws + off; off += (bytes + 255) & ~(size_t)255; return p;
    };
    float* A   = (float*)alloc((size_t)N_NODES * 64 * 4);
    float* Bb  = (float*)alloc((size_t)N_NODES * 64 * 4);
    float* Cc  = (float*)alloc((size_t)N_NODES * 64 * 4);
    float* D   = (float*)alloc((size_t)N_NODES * 4);
    float* XS  = (float*)alloc((size_t)B_BATCH * 256 * 4);
    int*   bsum = (int*)alloc(256 * 4);
    char*  csr  = alloc(14 * 1024 * 1024);  // overlay pool

    // graph-1 CSR carve (13.8 MB)
    int*   cnt1    = (int*)csr;
    int*   next1   = cnt1 + N_NODES;
    int*   rowptr1 = next1 + N_NODES;
    int*   src1    = rowptr1 + (N_NODES + 1);
    float* nw1     = (float*)(src1 + E_EDGES);
    // graph-2 + cover CSR carve (same pool, used after graph-1 CSR is dead; 7.2 MB)
    int*   cnt2    = (int*)csr;
    int*   next2   = cnt2 + C_CLUST;
    int*   rowptr2 = next2 + C_CLUST;
    int*   src2    = rowptr2 + (C_CLUST + 1);
    float* nw2     = (float*)(src2 + E2_EDGES);
    int*   cntP    = (int*)(nw2 + E2_EDGES);
    int*   nextP   = cntP + C_CLUST;
    int*   rowptrP = nextP + C_CLUST;
    int*   srcP    = rowptrP + (C_CLUST + 1);

    float* A2     = A  + (size_t)C_CLUST * 64;   // aggb2 (upper part of A)
    float* xp_sum = Bb;                          // Bb free after top gemm
    float* xp_max = Bb + (size_t)C_CLUST * 64;

    auto cdiv = [](long long a, long long b) { return (int)((a + b - 1) / b); };

    hipMemsetAsync(XS, 0, B_BATCH * 256 * 4, stream);

    // ---- graph 1: dis + CSR ----
    hipMemsetAsync(D, 0, N_NODES * 4, stream);
    hipMemsetAsync(cnt1, 0, N_NODES * 4, stream);
    deg_cnt_kernel<<<cdiv(E_EDGES, 256), 256, 0, stream>>>(ei1 + E_EDGES, w1, D, cnt1, E_EDGES);
    dis_kernel<<<cdiv(N_NODES, 256), 256, 0, stream>>>(D, N_NODES);
    scan1_kernel<<<cdiv(N_NODES, 1024), 256, 0, stream>>>(cnt1, next1, bsum, N_NODES);
    scan2_kernel<<<1, 256, 0, stream>>>(bsum, cdiv(N_NODES, 1024), rowptr1 + N_NODES);
    scan3_kernel<<<cdiv(N_NODES, 256), 256, 0, stream>>>(next1, bsum, rowptr1, next1, N_NODES);
    bucket_kernel<<<cdiv(E_EDGES, 256), 256, 0, stream>>>(ei1, w1, D, next1, src1, nw1, E_EDGES);

    // ---- block 1 ----
    gemm_kernel<64, false, false, false, false><<<cdiv(N_NODES, 64), 256, 0, stream>>>(
        x, nullptr, W_in0, nullptr, A, N_NODES);
    gcn_gather_kernel<<<cdiv((long long)N_NODES * 64, 256), 256, 0, stream>>>(
        A, rowptr1, src1, nw1, D, b_in0, Bb, N_NODES);
    gemm_kernel<64, true, false, false, false><<<cdiv(N_NODES, 64), 256, 0, stream>>>(
        Bb, nullptr, W_in1, nullptr, A, N_NODES);
    gcn_gather_kernel<<<cdiv((long long)N_NODES * 64, 256), 256, 0, stream>>>(
        A, rowptr1, src1, nw1, D, b_in1, Cc, N_NODES);
    gemm_kernel<128, true, true, true, true><<<cdiv(N_NODES, 64), 256, 0, stream>>>(
        Bb, Cc, Wl_in, bl_in, A, N_NODES);

    // ---- pooling 1 ----
    batch_pool_kernel<<<cdiv(N_NODES, 64), 64, 0, stream>>>(A, batch, N_NODES, XS, 0, 64);

    // ---- cover CSR + gather ----
    hipMemsetAsync(cntP, 0, C_CLUST * 4, stream);
    cnt_ids_kernel<<<cdiv(P_PAIRS, 256), 256, 0, stream>>>(coverc, cntP, P_PAIRS);
    scan1_kernel<<<cdiv(C_CLUST, 1024), 256, 0, stream>>>(cntP, nextP, bsum, C_CLUST);
    scan2_kernel<<<1, 256, 0, stream>>>(bsum, cdiv(C_CLUST, 1024), rowptrP + C_CLUST);
    scan3_kernel<<<cdiv(C_CLUST, 256), 256, 0, stream>>>(nextP, bsum, rowptrP, nextP, C_CLUST);
    bucketP_kernel<<<cdiv(P_PAIRS, 256), 256, 0, stream>>>(covern, coverc, nextP, srcP, P_PAIRS);
    cover_gather_kernel<<<cdiv((long long)C_CLUST * 64, 256), 256, 0, stream>>>(
        A, rowptrP, srcP, xp_sum, xp_max, C_CLUST);

    // ---- graph 2: dis + CSR ----
    hipMemsetAsync(D, 0, C_CLUST * 4, stream);
    hipMemsetAsync(cnt2, 0, C_CLUST * 4, stream);
    deg_cnt_kernel<<<cdiv(E2_EDGES, 256), 256, 0, stream>>>(ei2 + E2_EDGES, w2, D, cnt2, E2_EDGES);
    dis_kernel<<<cdiv(C_CLUST, 256), 256, 0, stream>>>(D, C_CLUST);
    scan1_kernel<<<cdiv(C_CLUST, 1024), 256, 0, stream>>>(cnt2, next2, bsum, C_CLUST);
    scan2_kernel<<<1, 256, 0, stream>>>(bsum, cdiv(C_CLUST, 1024), rowptr2 + C_CLUST);
    scan3_kernel<<<cdiv(C_CLUST, 256), 256, 0, stream>>>(next2, bsum, rowptr2, next2, C_CLUST);
    bucket_kernel<<<cdiv(E2_EDGES, 256), 256, 0, stream>>>(ei2, w2, D, next2, src2, nw2, E2_EDGES);

    // ---- block 2 ----
    gemm_kernel<128, false, false, true, false><<<cdiv(C_CLUST, 64), 256, 0, stream>>>(
        xp_sum, xp_max, W_b0, nullptr, Cc, C_CLUST);
    gcn_gather_kernel<<<cdiv((long long)C_CLUST * 64, 256), 256, 0, stream>>>(
        Cc, rowptr2, src2, nw2, D, b_b0, A, C_CLUST);
    gemm_kernel<64, true, false, false, false><<<cdiv(C_CLUST, 64), 256, 0, stream>>>(
        A, nullptr, W_b1, nullptr, Cc, C_CLUST);
    gcn_gather_kernel<<<cdiv((long long)C_CLUST * 64, 256), 256, 0, stream>>>(
        Cc, rowptr2, src2, nw2, D, b_b1, A2, C_CLUST);
    gemm_kernel<128, true, true, true, true><<<cdiv(C_CLUST, 64), 256, 0, stream>>>(
        A, A2, Wl_b, bl_b, Cc, C_CLUST);

    // ---- pooling 2 ----
    batch_pool_kernel<<<cdiv(C_CLUST, 64), 64, 0, stream>>>(Cc, batch2, C_CLUST, XS, 128, 64);

    // ---- head ----
    head_kernel<<<1, 256, 0, stream>>>(XS, gamma, beta, lin1W, lin1b, lin2W, lin2b, out);
}

// Round 6
// 927.726 us; speedup vs baseline: 2.0202x; 1.0934x over previous
//
#include <hip/hip_runtime.h>

#define N_NODES 150000
#define E_EDGES 1500000
#define C_CLUST 50000
#define P_PAIRS 300000
#define E2_EDGES 600000
#define B_BATCH 16
#define EPS_ 1e-5f

static __device__ __forceinline__ void atomicMaxFloatPos(float* addr, float v) {
    // valid for non-negative floats (bit pattern monotone); init must be 0.0f
    atomicMax((int*)addr, __float_as_int(v));
}

// ---------------- histogram (1 int atomic per element) ----------------

__global__ void cnt_ids_kernel(const int* __restrict__ ids, int* __restrict__ cnt, int P) {
    int p = blockIdx.x * blockDim.x + threadIdx.x;
    if (p < P) atomicAdd(&cnt[ids[p]], 1);
}

// ---------------- exclusive scan (3 kernels) ----------------
__global__ __launch_bounds__(256) void scan1_kernel(const int* __restrict__ cnt,
                                                    int* __restrict__ exc,
                                                    int* __restrict__ bsum, int n) {
    __shared__ int sh[256];
    int t = threadIdx.x;
    int base = blockIdx.x * 1024 + t * 4;
    int v[4];
    #pragma unroll
    for (int i = 0; i < 4; ++i) { int idx = base + i; v[i] = (idx < n) ? cnt[idx] : 0; }
    int tsum = v[0] + v[1] + v[2] + v[3];
    sh[t] = tsum; __syncthreads();
    for (int o = 1; o < 256; o <<= 1) {
        int add = (t >= o) ? sh[t - o] : 0;
        __syncthreads();
        sh[t] += add;
        __syncthreads();
    }
    int run = sh[t] - tsum;  // exclusive prefix for this thread
    #pragma unroll
    for (int i = 0; i < 4; ++i) { int idx = base + i; if (idx < n) exc[idx] = run; run += v[i]; }
    if (t == 255) bsum[blockIdx.x] = sh[255];
}

__global__ __launch_bounds__(256) void scan2_kernel(int* __restrict__ bsum, int nb,
                                                    int* __restrict__ total_out) {
    __shared__ int sh[256];
    int t = threadIdx.x;
    int val = (t < nb) ? bsum[t] : 0;
    sh[t] = val; __syncthreads();
    for (int o = 1; o < 256; o <<= 1) {
        int add = (t >= o) ? sh[t - o] : 0;
        __syncthreads();
        sh[t] += add;
        __syncthreads();
    }
    if (t < nb) bsum[t] = sh[t] - val;            // exclusive
    if (t == nb - 1) *total_out = sh[t];          // grand total -> rowptr[n]
}

__global__ void scan3_kernel(const int* __restrict__ exc, const int* __restrict__ bsum,
                             int* __restrict__ rowptr, int* __restrict__ next, int n) {
    int i = blockIdx.x * blockDim.x + threadIdx.x;
    if (i < n) {
        int v = exc[i] + bsum[i >> 10];
        rowptr[i] = v;
        next[i] = v;
    }
}

// ---------------- bucketing (raw edge weight; no dis dependency) ----------------

__global__ void bucket_kernel(const int* __restrict__ ei, const float* __restrict__ ew,
                              int* __restrict__ next, int* __restrict__ src,
                              float* __restrict__ ewc, int E) {
    int e = blockIdx.x * blockDim.x + threadIdx.x;
    if (e >= E) return;
    int r = ei[e], c = ei[E + e];
    int pos = atomicAdd(&next[c], 1);
    src[pos] = r;
    ewc[pos] = ew[e];
}

__global__ void bucketP_kernel(const int* __restrict__ cn, const int* __restrict__ cc,
                               int* __restrict__ next, int* __restrict__ srcn, int P) {
    int p = blockIdx.x * blockDim.x + threadIdx.x;
    if (p >= P) return;
    int pos = atomicAdd(&next[cc[p]], 1);
    srcn[pos] = cn[p];
}

// ---------------- dis from CSR: dis[c] = rsqrt(1 + sum_row ewc) ----------------

__global__ void dis_csr_kernel(const int* __restrict__ rowptr, const float* __restrict__ ewc,
                               float* __restrict__ dis, int n) {
    int c = blockIdx.x * blockDim.x + threadIdx.x;
    if (c >= n) return;
    int j0 = rowptr[c], j1 = rowptr[c + 1];
    float s = 0.f;
    for (int j = j0; j < j1; ++j) s += ewc[j];
    dis[c] = rsqrtf(s + 1.0f);   // +1 = self-loop weight, always > 0
}

// ---------------- nw in place: ewc[j] -> dis[src[j]] * ewc[j] * dis[c] ----------------

__global__ void nw_csr_kernel(const int* __restrict__ rowptr, const int* __restrict__ src,
                              float* __restrict__ ewc, const float* __restrict__ dis, int n) {
    int c = blockIdx.x * blockDim.x + threadIdx.x;
    if (c >= n) return;
    float dc = dis[c];
    int j0 = rowptr[c], j1 = rowptr[c + 1];
    for (int j = j0; j < j1; ++j)
        ewc[j] = dis[src[j]] * ewc[j] * dc;   // exact product order as reference
}

// ---------------- GCN gather: out[c] = bias + dis[c]^2*h[c] + sum nw[j]*h[src[j]] ----------------

__global__ void gcn_gather_kernel(const float* __restrict__ h, const int* __restrict__ rowptr,
                                  const int* __restrict__ src, const float* __restrict__ nw,
                                  const float* __restrict__ dis, const float* __restrict__ bias,
                                  float* __restrict__ out, int n) {
    int t = blockIdx.x * blockDim.x + threadIdx.x;
    int c = t >> 6, lane = t & 63;
    if (c >= n) return;
    float d = dis[c];
    float acc = bias[lane] + d * d * h[(size_t)c * 64 + lane];
    int j = rowptr[c], e1 = rowptr[c + 1];
    for (; j + 3 < e1; j += 4) {
        int   r0 = src[j],  r1 = src[j + 1], r2 = src[j + 2], r3 = src[j + 3];
        float w0 = nw[j],   w1 = nw[j + 1],  w2 = nw[j + 2],  w3 = nw[j + 3];
        float h0 = h[(size_t)r0 * 64 + lane];
        float h1 = h[(size_t)r1 * 64 + lane];
        float h2 = h[(size_t)r2 * 64 + lane];
        float h3 = h[(size_t)r3 * 64 + lane];
        acc += w0 * h0; acc += w1 * h1; acc += w2 * h2; acc += w3 * h3;
    }
    for (; j < e1; ++j) acc += nw[j] * h[(size_t)src[j] * 64 + lane];
    out[(size_t)c * 64 + lane] = acc;
}

// cover gather: sum + max per cluster, no atomics, no init needed
__global__ void cover_gather_kernel(const float* __restrict__ X, const int* __restrict__ rowptr,
                                    const int* __restrict__ srcn, float* __restrict__ xp_sum,
                                    float* __restrict__ xp_max, int C) {
    int t = blockIdx.x * blockDim.x + threadIdx.x;
    int c = t >> 6, lane = t & 63;
    if (c >= C) return;
    float s = 0.f, m = 0.f;
    int j = rowptr[c], e1 = rowptr[c + 1];
    for (; j + 1 < e1; j += 2) {
        float v0 = X[(size_t)srcn[j] * 64 + lane];
        float v1 = X[(size_t)srcn[j + 1] * 64 + lane];
        s += v0 + v1; m = fmaxf(m, fmaxf(v0, v1));
    }
    if (j < e1) {
        float v = X[(size_t)srcn[j] * 64 + lane];
        s += v; m = fmaxf(m, v);
    }
    xp_sum[(size_t)c * 64 + lane] = s;
    xp_max[(size_t)c * 64 + lane] = m;
}

// ---------------- GEMM: Y[n x 64] = (relu_in? relu(X) : X) @ W[K x 64] (+bias)(relu_out?) ----------------

template<int K, bool RELU_IN, bool RELU_OUT, bool HAS_X2, bool HAS_BIAS>
__global__ __launch_bounds__(256) void gemm_kernel(const float* __restrict__ X1,
                                                   const float* __restrict__ X2,
                                                   const float* __restrict__ W,
                                                   const float* __restrict__ bias,
                                                   float* __restrict__ Y, int n) {
    constexpr int KP = K + 4;
    __shared__ float Xs[64 * KP];
    __shared__ float Ws[K * 64];
    const int tid = threadIdx.x;
    const int r0 = blockIdx.x * 64;

    for (int i = tid; i < K * 16; i += 256)
        ((float4*)Ws)[i] = ((const float4*)W)[i];

    for (int i = tid; i < 16 * K; i += 256) {
        int row = i / (K / 4);
        int k4  = (i % (K / 4)) * 4;
        int r = r0 + row;
        float4 v = make_float4(0.f, 0.f, 0.f, 0.f);
        if (r < n) {
            const float* s = (HAS_X2 && k4 >= 64) ? (X2 + (size_t)r * 64 + (k4 - 64))
                                                  : (X1 + (size_t)r * 64 + k4);
            v = *(const float4*)s;
            if (RELU_IN) {
                v.x = fmaxf(v.x, 0.f); v.y = fmaxf(v.y, 0.f);
                v.z = fmaxf(v.z, 0.f); v.w = fmaxf(v.w, 0.f);
            }
        }
        *(float4*)&Xs[row * KP + k4] = v;
    }
    __syncthreads();

    const int tx = tid & 15, ty = tid >> 4;
    const int c0 = tx * 4, rl = ty * 4;
    float acc[4][4] = {};

    for (int k = 0; k < K; k += 4) {
        float4 xv[4], wv[4];
        #pragma unroll
        for (int i = 0; i < 4; ++i) xv[i] = *(const float4*)&Xs[(rl + i) * KP + k];
        #pragma unroll
        for (int i = 0; i < 4; ++i) wv[i] = *(const float4*)&Ws[(k + i) * 64 + c0];
        #pragma unroll
        for (int i = 0; i < 4; ++i) {
            const float* xp = (const float*)&xv[i];
            #pragma unroll
            for (int kk = 0; kk < 4; ++kk) {
                const float* wp = (const float*)&wv[kk];
                #pragma unroll
                for (int j = 0; j < 4; ++j) acc[i][j] += xp[kk] * wp[j];
            }
        }
    }

    #pragma unroll
    for (int i = 0; i < 4; ++i) {
        int r = r0 + rl + i;
        if (r < n) {
            float o[4];
            #pragma unroll
            for (int j = 0; j < 4; ++j) {
                o[j] = acc[i][j];
                if (HAS_BIAS) o[j] += bias[c0 + j];
                if (RELU_OUT) o[j] = fmaxf(o[j], 0.f);
            }
            *(float4*)&Y[(size_t)r * 64 + c0] = make_float4(o[0], o[1], o[2], o[3]);
        }
    }
}

// ---------------- sorted-segment batch pooling ----------------

__global__ void batch_pool_kernel(const float* __restrict__ X, const int* __restrict__ batch,
                                  int n, float* __restrict__ xs, int col_off, int rows_per_block) {
    int lane = threadIdx.x;  // 64 threads
    int rstart = blockIdx.x * rows_per_block;
    if (rstart >= n) return;
    int rend = min(rstart + rows_per_block, n);
    float s = 0.f, m = 0.f;
    int cur = batch[rstart];
    for (int r = rstart; r < rend; ++r) {
        int b = batch[r];
        if (b != cur) {
            atomicAdd(&xs[cur * 256 + col_off + lane], s);
            atomicMaxFloatPos(&xs[cur * 256 + col_off + 64 + lane], m);
            s = 0.f; m = 0.f; cur = b;
        }
        float v = X[(size_t)r * 64 + lane];
        s += v; m = fmaxf(m, v);
    }
    atomicAdd(&xs[cur * 256 + col_off + lane], s);
    atomicMaxFloatPos(&xs[cur * 256 + col_off + 64 + lane], m);
}

// ---------------- head: BN -> lin1+relu -> lin2 -> softmax ----------------

__global__ __launch_bounds__(256) void head_kernel(const float* __restrict__ xs,
    const float* __restrict__ gamma, const float* __restrict__ beta,
    const float* __restrict__ W1, const float* __restrict__ b1,
    const float* __restrict__ W2, const float* __restrict__ b2,
    float* __restrict__ out) {
    __shared__ float hn[16][256];
    __shared__ float h2[16][64];
    __shared__ float logits[16][10];
    int t = threadIdx.x;

    float v[16];
    float mu = 0.f;
    #pragma unroll
    for (int b = 0; b < 16; ++b) { v[b] = xs[b * 256 + t]; mu += v[b]; }
    mu *= (1.f / 16.f);
    float var = 0.f;
    #pragma unroll
    for (int b = 0; b < 16; ++b) { float d = v[b] - mu; var += d * d; }
    var *= (1.f / 16.f);
    float sc = rsqrtf(var + EPS_) * gamma[t];
    float bt = beta[t];
    #pragma unroll
    for (int b = 0; b < 16; ++b) hn[b][t] = (v[b] - mu) * sc + bt;
    __syncthreads();

    {
        int c = t & 63, bg = t >> 6;
        for (int j = 0; j < 4; ++j) {
            int b = bg * 4 + j;
            float acc = b1[c];
            for (int k = 0; k < 256; ++k) acc += hn[b][k] * W1[k * 64 + c];
            h2[b][c] = fmaxf(acc, 0.f);
        }
    }
    __syncthreads();

    if (t < 160) {
        int b = t / 10, c = t % 10;
        float acc = b2[c];
        for (int k = 0; k < 64; ++k) acc += h2[b][k] * W2[k * 10 + c];
        logits[b][c] = acc;
    }
    __syncthreads();

    if (t < 16) {
        float m = -1e30f;
        for (int c = 0; c < 10; ++c) m = fmaxf(m, logits[t][c]);
        float s = 0.f;
        float e[10];
        for (int c = 0; c < 10; ++c) { e[c] = expf(logits[t][c] - m); s += e[c]; }
        float inv = 1.f / s;
        for (int c = 0; c < 10; ++c) out[t * 10 + c] = e[c] * inv;
    }
}

extern "C" void kernel_launch(void* const* d_in, const int* in_sizes, int n_in,
                              void* d_out, int out_size, void* d_ws, size_t ws_size,
                              hipStream_t stream) {
    (void)in_sizes; (void)n_in; (void)out_size; (void)ws_size;
    const float* x      = (const float*)d_in[0];
    const int*   ei1    = (const int*)d_in[1];
    const float* w1     = (const float*)d_in[2];
    const int*   batch  = (const int*)d_in[3];
    const int*   covern = (const int*)d_in[4];
    const int*   coverc = (const int*)d_in[5];
    const int*   ei2    = (const int*)d_in[6];
    const float* w2     = (const float*)d_in[7];
    const int*   batch2 = (const int*)d_in[8];
    const float* W_in0  = (const float*)d_in[9];
    const float* b_in0  = (const float*)d_in[10];
    const float* W_in1  = (const float*)d_in[11];
    const float* b_in1  = (const float*)d_in[12];
    const float* Wl_in  = (const float*)d_in[13];
    const float* bl_in  = (const float*)d_in[14];
    const float* W_b0   = (const float*)d_in[15];
    const float* b_b0   = (const float*)d_in[16];
    const float* W_b1   = (const float*)d_in[17];
    const float* b_b1   = (const float*)d_in[18];
    const float* Wl_b   = (const float*)d_in[19];
    const float* bl_b   = (const float*)d_in[20];
    const float* gamma  = (const float*)d_in[21];
    const float* beta   = (const float*)d_in[22];
    const float* lin1W  = (const float*)d_in[23];
    const float* lin1b  = (const float*)d_in[24];
    const float* lin2W  = (const float*)d_in[25];
    const float* lin2b  = (const float*)d_in[26];
    float* out = (float*)d_out;

    char* ws = (char*)d_ws;
    size_t off = 0;
    auto alloc = [&](size_t bytes) {
        char* p = ws + off; off += (bytes + 255) & ~(size_t)255; return p;
    };
    float* A   = (float*)alloc((size_t)N_NODES * 64 * 4);
    float* Bb  = (float*)alloc((size_t)N_NODES * 64 * 4);
    float* Cc  = (float*)alloc((size_t)N_NODES * 64 * 4);
    float* D   = (float*)alloc((size_t)N_NODES * 4);   // dis
    float* XS  = (float*)alloc((size_t)B_BATCH * 256 * 4);
    int*   bsum = (int*)alloc(256 * 4);
    char*  csr  = alloc(14 * 1024 * 1024);  // overlay pool

    // graph-1 CSR carve (13.8 MB)
    int*   cnt1    = (int*)csr;
    int*   next1   = cnt1 + N_NODES;
    int*   rowptr1 = next1 + N_NODES;
    int*   src1    = rowptr1 + (N_NODES + 1);
    float* nw1     = (float*)(src1 + E_EDGES);
    // graph-2 + cover CSR carve (same pool, used after graph-1 CSR is dead; 7.2 MB)
    int*   cnt2    = (int*)csr;
    int*   next2   = cnt2 + C_CLUST;
    int*   rowptr2 = next2 + C_CLUST;
    int*   src2    = rowptr2 + (C_CLUST + 1);
    float* nw2     = (float*)(src2 + E2_EDGES);
    int*   cntP    = (int*)(nw2 + E2_EDGES);
    int*   nextP   = cntP + C_CLUST;
    int*   rowptrP = nextP + C_CLUST;
    int*   srcP    = rowptrP + (C_CLUST + 1);

    float* A2     = A  + (size_t)C_CLUST * 64;   // aggb2 (upper part of A)
    float* xp_sum = Bb;                          // Bb free after top gemm
    float* xp_max = Bb + (size_t)C_CLUST * 64;

    auto cdiv = [](long long a, long long b) { return (int)((a + b - 1) / b); };

    hipMemsetAsync(XS, 0, B_BATCH * 256 * 4, stream);

    // ---- graph 1 CSR: cnt -> scan -> bucket(raw) -> dis -> nw ----
    hipMemsetAsync(cnt1, 0, N_NODES * 4, stream);
    cnt_ids_kernel<<<cdiv(E_EDGES, 256), 256, 0, stream>>>(ei1 + E_EDGES, cnt1, E_EDGES);
    scan1_kernel<<<cdiv(N_NODES, 1024), 256, 0, stream>>>(cnt1, next1, bsum, N_NODES);
    scan2_kernel<<<1, 256, 0, stream>>>(bsum, cdiv(N_NODES, 1024), rowptr1 + N_NODES);
    scan3_kernel<<<cdiv(N_NODES, 256), 256, 0, stream>>>(next1, bsum, rowptr1, next1, N_NODES);
    bucket_kernel<<<cdiv(E_EDGES, 256), 256, 0, stream>>>(ei1, w1, next1, src1, nw1, E_EDGES);
    dis_csr_kernel<<<cdiv(N_NODES, 256), 256, 0, stream>>>(rowptr1, nw1, D, N_NODES);
    nw_csr_kernel<<<cdiv(N_NODES, 256), 256, 0, stream>>>(rowptr1, src1, nw1, D, N_NODES);

    // ---- block 1 ----
    gemm_kernel<64, false, false, false, false><<<cdiv(N_NODES, 64), 256, 0, stream>>>(
        x, nullptr, W_in0, nullptr, A, N_NODES);
    gcn_gather_kernel<<<cdiv((long long)N_NODES * 64, 256), 256, 0, stream>>>(
        A, rowptr1, src1, nw1, D, b_in0, Bb, N_NODES);
    gemm_kernel<64, true, false, false, false><<<cdiv(N_NODES, 64), 256, 0, stream>>>(
        Bb, nullptr, W_in1, nullptr, A, N_NODES);
    gcn_gather_kernel<<<cdiv((long long)N_NODES * 64, 256), 256, 0, stream>>>(
        A, rowptr1, src1, nw1, D, b_in1, Cc, N_NODES);
    gemm_kernel<128, true, true, true, true><<<cdiv(N_NODES, 64), 256, 0, stream>>>(
        Bb, Cc, Wl_in, bl_in, A, N_NODES);

    // ---- pooling 1 ----
    batch_pool_kernel<<<cdiv(N_NODES, 64), 64, 0, stream>>>(A, batch, N_NODES, XS, 0, 64);

    // ---- cover CSR + gather ----
    hipMemsetAsync(cntP, 0, C_CLUST * 4, stream);
    cnt_ids_kernel<<<cdiv(P_PAIRS, 256), 256, 0, stream>>>(coverc, cntP, P_PAIRS);
    scan1_kernel<<<cdiv(C_CLUST, 1024), 256, 0, stream>>>(cntP, nextP, bsum, C_CLUST);
    scan2_kernel<<<1, 256, 0, stream>>>(bsum, cdiv(C_CLUST, 1024), rowptrP + C_CLUST);
    scan3_kernel<<<cdiv(C_CLUST, 256), 256, 0, stream>>>(nextP, bsum, rowptrP, nextP, C_CLUST);
    bucketP_kernel<<<cdiv(P_PAIRS, 256), 256, 0, stream>>>(covern, coverc, nextP, srcP, P_PAIRS);
    cover_gather_kernel<<<cdiv((long long)C_CLUST * 64, 256), 256, 0, stream>>>(
        A, rowptrP, srcP, xp_sum, xp_max, C_CLUST);

    // ---- graph 2 CSR ----
    hipMemsetAsync(cnt2, 0, C_CLUST * 4, stream);
    cnt_ids_kernel<<<cdiv(E2_EDGES, 256), 256, 0, stream>>>(ei2 + E2_EDGES, cnt2, E2_EDGES);
    scan1_kernel<<<cdiv(C_CLUST, 1024), 256, 0, stream>>>(cnt2, next2, bsum, C_CLUST);
    scan2_kernel<<<1, 256, 0, stream>>>(bsum, cdiv(C_CLUST, 1024), rowptr2 + C_CLUST);
    scan3_kernel<<<cdiv(C_CLUST, 256), 256, 0, stream>>>(next2, bsum, rowptr2, next2, C_CLUST);
    bucket_kernel<<<cdiv(E2_EDGES, 256), 256, 0, stream>>>(ei2, w2, next2, src2, nw2, E2_EDGES);
    dis_csr_kernel<<<cdiv(C_CLUST, 256), 256, 0, stream>>>(rowptr2, nw2, D, C_CLUST);
    nw_csr_kernel<<<cdiv(C_CLUST, 256), 256, 0, stream>>>(rowptr2, src2, nw2, D, C_CLUST);

    // ---- block 2 ----
    gemm_kernel<128, false, false, true, false><<<cdiv(C_CLUST, 64), 256, 0, stream>>>(
        xp_sum, xp_max, W_b0, nullptr, Cc, C_CLUST);
    gcn_gather_kernel<<<cdiv((long long)C_CLUST * 64, 256), 256, 0, stream>>>(
        Cc, rowptr2, src2, nw2, D, b_b0, A, C_CLUST);
    gemm_kernel<64, true, false, false, false><<<cdiv(C_CLUST, 64), 256, 0, stream>>>(
        A, nullptr, W_b1, nullptr, Cc, C_CLUST);
    gcn_gather_kernel<<<cdiv((long long)C_CLUST * 64, 256), 256, 0, stream>>>(
        Cc, rowptr2, src2, nw2, D, b_b1, A2, C_CLUST);
    gemm_kernel<128, true, true, true, true><<<cdiv(C_CLUST, 64), 256, 0, stream>>>(
        A, A2, Wl_b, bl_b, Cc, C_CLUST);

    // ---- pooling 2 ----
    batch_pool_kernel<<<cdiv(C_CLUST, 64), 64, 0, stream>>>(Cc, batch2, C_CLUST, XS, 128, 64);

    // ---- head ----
    head_kernel<<<1, 256, 0, stream>>>(XS, gamma, beta, lin1W, lin1b, lin2W, lin2b, out);
}